// Round 1
// 628.695 us; speedup vs baseline: 1.0260x; 1.0260x over previous
//
#include <hip/hip_runtime.h>
#include <stdint.h>

// Problem constants
#define E_ 64
#define H_ 1024
#define I_ 768
#define T_ 8192

typedef __attribute__((ext_vector_type(4))) float floatx4;
typedef __attribute__((ext_vector_type(8))) short bf16x8;

__device__ inline unsigned short f2bf(float f) {
  union { float f; uint32_t u; } v; v.f = f;
  return (unsigned short)((v.u + 0x7FFFu + ((v.u >> 16) & 1u)) >> 16); // RNE
}
__device__ inline float bf2f(unsigned short s) {
  union { uint32_t u; float f; } v; v.u = ((uint32_t)s) << 16;
  return v.f;
}

// async global->LDS, 16B per lane. LDS dest must be wave-uniform base + lane*16.
__device__ inline void gload16(const void* g, void* l) {
  __builtin_amdgcn_global_load_lds(
      (const __attribute__((address_space(1))) void*)g,
      (__attribute__((address_space(3))) void*)l, 16, 0, 0);
}

// ---------------- prep: x fp32 -> bf16, and expert prefix offsets ----------------
__global__ void k_prep(const float* __restrict__ x, unsigned short* __restrict__ xb,
                       const int* __restrict__ cnts, int* __restrict__ offs) {
  int i = blockIdx.x * 256 + threadIdx.x;  // 4 elems per thread, T_*H_/4 threads exactly
  float4 v = ((const float4*)x)[i];
  ushort4 o;
  o.x = f2bf(v.x); o.y = f2bf(v.y); o.z = f2bf(v.z); o.w = f2bf(v.w);
  ((ushort4*)xb)[i] = o;
  if (i == 0) {
    int s = 0; offs[0] = 0;
    for (int e = 0; e < E_; ++e) { s += cnts[e]; offs[e + 1] = s; }
  }
}

// ---------------- GEMM1: gate/up fused + SwiGLU -> h (bf16) ----------------
// block tile: 256 rows x 64 cols, K = 1024, BK = 32. 4 waves, wave w owns rows [w*64, w*64+64).
// Double-buffered LDS: stage kt+1 while computing kt; counted vmcnt(8) keeps the
// prefetch in flight across the raw s_barrier (never drain vmcnt(0) in the main loop).
__global__ __launch_bounds__(256, 2) void k_gemm1(
    const unsigned short* __restrict__ xb, const float* __restrict__ w1,
    const float* __restrict__ w3, unsigned short* __restrict__ h,
    const int* __restrict__ offs) {
  __shared__ unsigned short As[2][256 * 32];  // [m][k] bf16 (16KB each)
  __shared__ float Bs1[2][32 * 64];           // [k][n] fp32 (8KB each)
  __shared__ float Bs3[2][32 * 64];           // total 64KB -> 2 blocks/CU

  const int tid = threadIdx.x;
  const int wv = tid >> 6;
  const int l = tid & 63;
  const int lq = l >> 4;   // quad
  const int ln = l & 15;
  const int e = blockIdx.x / (I_ / 64);
  const int n0 = (blockIdx.x % (I_ / 64)) * 64;
  const int off = offs[e];
  const int cnt = offs[e + 1] - off;

  // B staging source: thread t covers k-row (tid>>4) (+16 on 2nd round), 16B of n
  const float* b1p = w1 + (size_t)e * (H_ * I_) + (size_t)(tid >> 4) * I_ + n0 + (tid & 15) * 4;
  const float* b3p = w3 + (size_t)e * (H_ * I_) + (size_t)(tid >> 4) * I_ + n0 + (tid & 15) * 4;

  for (int mb = 0; mb < cnt; mb += 256) {
    const int m_here = (cnt - mb) < 256 ? (cnt - mb) : 256;
    const bool active = (wv * 64) < m_here;

    const unsigned short* aptr[4];
#pragma unroll
    for (int r = 0; r < 4; ++r) {
      int row = off + mb + r * 64 + (tid >> 2);
      row = row < (T_ - 1) ? row : (T_ - 1);  // clamp; garbage rows masked at store
      aptr[r] = xb + (size_t)row * H_ + (tid & 3) * 8;
    }

    // stage K-step kt into buffer buf: 8 global_load_lds per wave (4 A + 2 B1 + 2 B3)
    auto STG = [&](int kt, int buf) {
#pragma unroll
      for (int r = 0; r < 4; ++r)
        gload16(aptr[r] + kt * 32, &As[buf][tid * 8 + r * 2048]);
#pragma unroll
      for (int r = 0; r < 2; ++r) {
        gload16(b1p + (size_t)(kt * 32 + r * 16) * I_, &Bs1[buf][tid * 4 + r * 1024]);
        gload16(b3p + (size_t)(kt * 32 + r * 16) * I_, &Bs3[buf][tid * 4 + r * 1024]);
      }
    };

    floatx4 accG[4][4], accU[4][4];
#pragma unroll
    for (int i2 = 0; i2 < 4; ++i2)
#pragma unroll
      for (int j2 = 0; j2 < 4; ++j2) {
        accG[i2][j2] = (floatx4){0.f, 0.f, 0.f, 0.f};
        accU[i2][j2] = (floatx4){0.f, 0.f, 0.f, 0.f};
      }

    const int NK = H_ / 32;  // 32
    STG(0, 0);               // prologue prefetch
    for (int kt = 0; kt < NK; ++kt) {
      const int cur = kt & 1;
      if (kt + 1 < NK) {
        STG(kt + 1, cur ^ 1);                             // issue next tile first
        asm volatile("s_waitcnt vmcnt(8)" ::: "memory");  // kt's 8 landed; kt+1's stay in flight
      } else {
        asm volatile("s_waitcnt vmcnt(0)" ::: "memory");
      }
      __builtin_amdgcn_s_barrier();          // all waves' staging of cur visible
      asm volatile("" ::: "memory");         // no LDS-read hoisting above the barrier

      if (active) {
        const unsigned short* Asc = As[cur];
        const float* B1c = Bs1[cur];
        const float* B3c = Bs3[cur];
        bf16x8 bG[4], bU[4];
#pragma unroll
        for (int nf = 0; nf < 4; ++nf) {
          const float* p1 = &B1c[(lq * 8) * 64 + nf * 16 + ln];
          const float* p3 = &B3c[(lq * 8) * 64 + nf * 16 + ln];
          bf16x8 t1, t3;
#pragma unroll
          for (int j = 0; j < 8; ++j) {
            t1[j] = (short)f2bf(p1[j * 64]);
            t3[j] = (short)f2bf(p3[j * 64]);
          }
          bG[nf] = t1; bU[nf] = t3;
        }
#pragma unroll
        for (int mf = 0; mf < 4; ++mf) {
          const bf16x8 af = *(const bf16x8*)&Asc[(size_t)(wv * 64 + mf * 16 + ln) * 32 + lq * 8];
#pragma unroll
          for (int nf = 0; nf < 4; ++nf) {
            accG[mf][nf] = __builtin_amdgcn_mfma_f32_16x16x32_bf16(af, bG[nf], accG[mf][nf], 0, 0, 0);
            accU[mf][nf] = __builtin_amdgcn_mfma_f32_16x16x32_bf16(af, bU[nf], accU[mf][nf], 0, 0, 0);
          }
        }
      }
      asm volatile("" ::: "memory");         // no LDS-read sinking below the barrier
      __builtin_amdgcn_s_barrier();          // cur free for overwrite at kt+2's stage
    }

    if (active) {
#pragma unroll
      for (int mf = 0; mf < 4; ++mf)
#pragma unroll
        for (int nf = 0; nf < 4; ++nf)
#pragma unroll
          for (int r = 0; r < 4; ++r) {
            int row_l = wv * 64 + mf * 16 + lq * 4 + r;  // C/D: row=quad*4+reg, col=lane&15
            if (row_l < m_here) {
              float g = bf2f(f2bf(accG[mf][nf][r]));  // match ref: gate/up rounded to bf16
              float u = bf2f(f2bf(accU[mf][nf][r]));
              float hv = (g / (1.0f + __expf(-g))) * u;  // silu(g)*u
              h[(size_t)(off + mb + row_l) * I_ + n0 + nf * 16 + ln] = f2bf(hv);
            }
          }
    }
    // drain stores so the (rare) next mb iteration's vmcnt accounting stays exact
    asm volatile("s_waitcnt vmcnt(0)" ::: "memory");
  }
}

// ---------------- GEMM2: out = h @ w2 (fp32 out) ----------------
__global__ __launch_bounds__(256, 3) void k_gemm2(
    const unsigned short* __restrict__ h, const float* __restrict__ w2,
    float* __restrict__ out, const int* __restrict__ offs) {
  __shared__ unsigned short As[2][256 * 32];  // 32KB
  __shared__ float Bs[2][32 * 64];            // 16KB -> 48KB total, 3 blocks/CU

  const int tid = threadIdx.x;
  const int wv = tid >> 6;
  const int l = tid & 63;
  const int lq = l >> 4;
  const int ln = l & 15;
  const int e = blockIdx.x / (H_ / 64);
  const int n0 = (blockIdx.x % (H_ / 64)) * 64;
  const int off = offs[e];
  const int cnt = offs[e + 1] - off;

  const float* b2p = w2 + (size_t)e * (I_ * H_) + (size_t)(tid >> 4) * H_ + n0 + (tid & 15) * 4;

  for (int mb = 0; mb < cnt; mb += 256) {
    const int m_here = (cnt - mb) < 256 ? (cnt - mb) : 256;
    const bool active = (wv * 64) < m_here;

    const unsigned short* aptr[4];
#pragma unroll
    for (int r = 0; r < 4; ++r) {
      int row = off + mb + r * 64 + (tid >> 2);
      row = row < (T_ - 1) ? row : (T_ - 1);
      aptr[r] = h + (size_t)row * I_ + (tid & 3) * 8;
    }

    auto STG = [&](int kt, int buf) {
#pragma unroll
      for (int r = 0; r < 4; ++r)
        gload16(aptr[r] + kt * 32, &As[buf][tid * 8 + r * 2048]);
#pragma unroll
      for (int r = 0; r < 2; ++r)
        gload16(b2p + (size_t)(kt * 32 + r * 16) * H_, &Bs[buf][tid * 4 + r * 1024]);
    };

    floatx4 acc[4][4];
#pragma unroll
    for (int i2 = 0; i2 < 4; ++i2)
#pragma unroll
      for (int j2 = 0; j2 < 4; ++j2) acc[i2][j2] = (floatx4){0.f, 0.f, 0.f, 0.f};

    const int NK = I_ / 32;  // 24
    STG(0, 0);
    for (int kt = 0; kt < NK; ++kt) {
      const int cur = kt & 1;
      if (kt + 1 < NK) {
        STG(kt + 1, cur ^ 1);                             // 6 loads per wave
        asm volatile("s_waitcnt vmcnt(6)" ::: "memory");  // kt's 6 landed
      } else {
        asm volatile("s_waitcnt vmcnt(0)" ::: "memory");
      }
      __builtin_amdgcn_s_barrier();
      asm volatile("" ::: "memory");

      if (active) {
        const unsigned short* Asc = As[cur];
        const float* Bc = Bs[cur];
        bf16x8 bF[4];
#pragma unroll
        for (int nf = 0; nf < 4; ++nf) {
          const float* p = &Bc[(lq * 8) * 64 + nf * 16 + ln];
          bf16x8 t;
#pragma unroll
          for (int j = 0; j < 8; ++j) t[j] = (short)f2bf(p[j * 64]);
          bF[nf] = t;
        }
#pragma unroll
        for (int mf = 0; mf < 4; ++mf) {
          const bf16x8 af = *(const bf16x8*)&Asc[(size_t)(wv * 64 + mf * 16 + ln) * 32 + lq * 8];
#pragma unroll
          for (int nf = 0; nf < 4; ++nf)
            acc[mf][nf] = __builtin_amdgcn_mfma_f32_16x16x32_bf16(af, bF[nf], acc[mf][nf], 0, 0, 0);
        }
      }
      asm volatile("" ::: "memory");
      __builtin_amdgcn_s_barrier();
    }

    if (active) {
#pragma unroll
      for (int mf = 0; mf < 4; ++mf)
#pragma unroll
        for (int nf = 0; nf < 4; ++nf)
#pragma unroll
          for (int r = 0; r < 4; ++r) {
            int row_l = wv * 64 + mf * 16 + lq * 4 + r;
            if (row_l < m_here)
              out[(size_t)(off + mb + row_l) * H_ + n0 + nf * 16 + ln] = acc[mf][nf][r];
          }
    }
    asm volatile("s_waitcnt vmcnt(0)" ::: "memory");
  }
}

extern "C" void kernel_launch(void* const* d_in, const int* in_sizes, int n_in,
                              void* d_out, int out_size, void* d_ws, size_t ws_size,
                              hipStream_t stream) {
  const float* x  = (const float*)d_in[0];
  const float* w1 = (const float*)d_in[1];
  const float* w2 = (const float*)d_in[2];
  const float* w3 = (const float*)d_in[3];
  const int* cnts = (const int*)d_in[4];
  float* out = (float*)d_out;

  char* ws = (char*)d_ws;
  int* offs = (int*)ws;                                        // 65 ints
  unsigned short* xb = (unsigned short*)(ws + 1024);           // 16 MB  (T_*H_ bf16)
  unsigned short* h  = (unsigned short*)(ws + 1024 + (size_t)T_ * H_ * 2);  // 12 MB (T_*I_ bf16)

  k_prep<<<(T_ * H_) / (256 * 4), 256, 0, stream>>>(x, xb, cnts, offs);
  k_gemm1<<<E_ * (I_ / 64), 256, 0, stream>>>(xb, w1, w3, h, offs);
  k_gemm2<<<E_ * (H_ / 64), 256, 0, stream>>>(h, w2, out, offs);
}

// Round 2
// 619.305 us; speedup vs baseline: 1.0416x; 1.0152x over previous
//
#include <hip/hip_runtime.h>
#include <stdint.h>

// Problem constants
#define E_ 64
#define H_ 1024
#define I_ 768
#define T_ 8192

typedef __attribute__((ext_vector_type(4))) float floatx4;
typedef __attribute__((ext_vector_type(8))) short bf16x8;

__device__ inline unsigned short f2bf(float f) {
  union { float f; uint32_t u; } v; v.f = f;
  return (unsigned short)((v.u + 0x7FFFu + ((v.u >> 16) & 1u)) >> 16); // RNE
}
__device__ inline float bf2f(unsigned short s) {
  union { uint32_t u; float f; } v; v.u = ((uint32_t)s) << 16;
  return v.f;
}

// async global->LDS, 16B per lane. LDS dest must be wave-uniform base + lane*16.
__device__ inline void gload16(const void* g, void* l) {
  __builtin_amdgcn_global_load_lds(
      (const __attribute__((address_space(1))) void*)g,
      (__attribute__((address_space(3))) void*)l, 16, 0, 0);
}

// 16B-slot index in a [64 rows][32 bf16] tile, XOR-swizzled so both the
// convert-phase writes (64 lanes = 64 rows, fixed chunk) and the frag reads
// (16 rows x 4 chunks) spread uniformly over the 8 bank-quads.
__device__ inline int bslot(int n, int c) { return n * 4 + (c ^ ((n >> 1) & 3)); }

// ---------------- prep: x fp32 -> bf16, and expert prefix offsets ----------------
__global__ void k_prep(const float* __restrict__ x, unsigned short* __restrict__ xb,
                       const int* __restrict__ cnts, int* __restrict__ offs) {
  int i = blockIdx.x * 256 + threadIdx.x;  // 4 elems per thread, T_*H_/4 threads exactly
  float4 v = ((const float4*)x)[i];
  ushort4 o;
  o.x = f2bf(v.x); o.y = f2bf(v.y); o.z = f2bf(v.z); o.w = f2bf(v.w);
  ((ushort4*)xb)[i] = o;
  if (i == 0) {
    int s = 0; offs[0] = 0;
    for (int e = 0; e < E_; ++e) { s += cnts[e]; offs[e + 1] = s; }
  }
}

// ---------------- GEMM1: gate/up fused + SwiGLU -> h (bf16) ----------------
// 256x64 tile, BK=32. B (w1,w3) is the only LDS traffic: fp32 DMA (double-buffered,
// counted vmcnt) -> block-shared convert to swizzled bf16 [n][k] -> b128 frag reads.
// A-frags (xb, L3-resident) load straight from global into registers.
__global__ __launch_bounds__(256, 2) void k_gemm1(
    const unsigned short* __restrict__ xb, const float* __restrict__ w1,
    const float* __restrict__ w3, unsigned short* __restrict__ h,
    const int* __restrict__ offs) {
  __shared__ __align__(16) float Bf[2][2][32 * 64];        // [buf][mat][k][n] fp32, 32 KB
  __shared__ __align__(16) unsigned short Bh[2][64 * 32];  // [mat][n][k] bf16 swizzled, 8 KB

  const int tid = threadIdx.x;
  const int wv = tid >> 6;
  const int l = tid & 63;
  const int lq = l >> 4;   // quad
  const int ln = l & 15;
  // XCD swizzle: group the 12 n-blocks of each expert on one XCD (768 = 8*96)
  const int bid = ((int)blockIdx.x & 7) * (E_ * (I_ / 64) / 8) + ((int)blockIdx.x >> 3);
  const int e = bid / (I_ / 64);
  const int n0 = (bid % (I_ / 64)) * 64;
  const int off = offs[e];
  const int cnt = offs[e + 1] - off;

  const int cn = tid & 63;  // convert: output row n
  const int ck = tid >> 6;  // convert: k-octet (8 k's)

  // B DMA source: thread t covers k-row (tid>>4) (+16 on 2nd round), 16B of n
  const float* b1p = w1 + (size_t)e * (H_ * I_) + (size_t)(tid >> 4) * I_ + n0 + (tid & 15) * 4;
  const float* b3p = w3 + (size_t)e * (H_ * I_) + (size_t)(tid >> 4) * I_ + n0 + (tid & 15) * 4;

  for (int mb = 0; mb < cnt; mb += 256) {
    const int m_here = (cnt - mb) < 256 ? (cnt - mb) : 256;
    const bool active = (wv * 64) < m_here;

    // A-frag row pointers (per mf); clamped rows masked at store
    const unsigned short* aF[4];
#pragma unroll
    for (int mf = 0; mf < 4; ++mf) {
      int row = off + mb + wv * 64 + mf * 16 + ln;
      row = row < (T_ - 1) ? row : (T_ - 1);
      aF[mf] = xb + (size_t)row * H_ + lq * 8;
    }

    // stage fp32 B K-step kt into Bf[buf] (linear; 4 loads/wave: 2 per matrix)
    auto STGB = [&](int kt, int buf) {
#pragma unroll
      for (int r = 0; r < 2; ++r) {
        gload16(b1p + (size_t)(kt * 32 + r * 16) * I_, &Bf[buf][0][tid * 4 + r * 1024]);
        gload16(b3p + (size_t)(kt * 32 + r * 16) * I_, &Bf[buf][1][tid * 4 + r * 1024]);
      }
    };

    floatx4 accG[4][4], accU[4][4];
#pragma unroll
    for (int i2 = 0; i2 < 4; ++i2)
#pragma unroll
      for (int j2 = 0; j2 < 4; ++j2) {
        accG[i2][j2] = (floatx4){0.f, 0.f, 0.f, 0.f};
        accU[i2][j2] = (floatx4){0.f, 0.f, 0.f, 0.f};
      }

    const int NK = H_ / 32;  // 32
    STGB(0, 0);
    STGB(1, 1);
    for (int kt = 0; kt < NK; ++kt) {
      const int cur = kt & 1;
      // FIFO per wave: [B(kt)x4, B(kt+1)x4] -> counted wait for B(kt) only
      if (kt == NK - 1) asm volatile("s_waitcnt vmcnt(0)" ::: "memory");
      else              asm volatile("s_waitcnt vmcnt(4)" ::: "memory");
      __builtin_amdgcn_s_barrier();   // everyone's B(kt) visible; prev frag reads done
      asm volatile("" ::: "memory");

      // block-shared convert: fp32 [k][n] -> bf16 [n][k] (swizzled slots)
      // reads: lane=cn -> bank cn%32, 2 lanes/bank = free; writes: b128, quad-uniform
#pragma unroll
      for (int m = 0; m < 2; ++m) {
        uint32_t dw[4];
#pragma unroll
        for (int d = 0; d < 4; ++d) {
          float v0 = Bf[cur][m][(ck * 8 + 2 * d) * 64 + cn];
          float v1 = Bf[cur][m][(ck * 8 + 2 * d + 1) * 64 + cn];
          dw[d] = (uint32_t)f2bf(v0) | ((uint32_t)f2bf(v1) << 16);
        }
        *(uint4*)&Bh[m][(size_t)bslot(cn, ck) * 8] = make_uint4(dw[0], dw[1], dw[2], dw[3]);
      }
      asm volatile("s_waitcnt lgkmcnt(0)" ::: "memory");  // converts visible before barrier
      __builtin_amdgcn_s_barrier();
      asm volatile("" ::: "memory");

      // A-frags from global (L3-resident xb) BEFORE next DMA issue, so the
      // compiler's pre-MFMA wait is counted (vmcnt(4)), not a drain.
      bf16x8 af[4];
      if (active) {
#pragma unroll
        for (int mf = 0; mf < 4; ++mf) af[mf] = *(const bf16x8*)(aF[mf] + kt * 32);
      }
      asm volatile("" ::: "memory");
      if (kt + 2 < NK) STGB(kt + 2, cur);  // Bf[cur] free: all converts passed barrier
      asm volatile("" ::: "memory");

      if (active) {
        bf16x8 bG[4], bU[4];
#pragma unroll
        for (int nf = 0; nf < 4; ++nf) {
          const int sl = bslot(nf * 16 + ln, lq) * 8;
          bG[nf] = *(const bf16x8*)&Bh[0][sl];
          bU[nf] = *(const bf16x8*)&Bh[1][sl];
        }
#pragma unroll
        for (int mf = 0; mf < 4; ++mf)
#pragma unroll
          for (int nf = 0; nf < 4; ++nf) {
            accG[mf][nf] = __builtin_amdgcn_mfma_f32_16x16x32_bf16(af[mf], bG[nf], accG[mf][nf], 0, 0, 0);
            accU[mf][nf] = __builtin_amdgcn_mfma_f32_16x16x32_bf16(af[mf], bU[nf], accU[mf][nf], 0, 0, 0);
          }
      }
    }

    if (active) {
#pragma unroll
      for (int mf = 0; mf < 4; ++mf)
#pragma unroll
        for (int nf = 0; nf < 4; ++nf)
#pragma unroll
          for (int r = 0; r < 4; ++r) {
            int row_l = wv * 64 + mf * 16 + lq * 4 + r;  // C/D: row=quad*4+reg, col=lane&15
            if (row_l < m_here) {
              float g = bf2f(f2bf(accG[mf][nf][r]));  // match ref: gate/up rounded to bf16
              float u = bf2f(f2bf(accU[mf][nf][r]));
              float hv = (g / (1.0f + __expf(-g))) * u;  // silu(g)*u
              h[(size_t)(off + mb + row_l) * I_ + n0 + nf * 16 + ln] = f2bf(hv);
            }
          }
    }
    asm volatile("s_waitcnt vmcnt(0)" ::: "memory");  // drain before next mb prologue
  }
}

// ---------------- GEMM2: out = h @ w2 (fp32 out) ----------------
__global__ __launch_bounds__(256, 3) void k_gemm2(
    const unsigned short* __restrict__ h, const float* __restrict__ w2,
    float* __restrict__ out, const int* __restrict__ offs) {
  __shared__ __align__(16) float Bf[2][32 * 64];        // [buf][k][n] fp32, 16 KB
  __shared__ __align__(16) unsigned short Bh[64 * 32];  // [n][k] bf16 swizzled, 4 KB

  const int tid = threadIdx.x;
  const int wv = tid >> 6;
  const int l = tid & 63;
  const int lq = l >> 4;
  const int ln = l & 15;
  const int bid = ((int)blockIdx.x & 7) * (E_ * (H_ / 64) / 8) + ((int)blockIdx.x >> 3);
  const int e = bid / (H_ / 64);
  const int n0 = (bid % (H_ / 64)) * 64;
  const int off = offs[e];
  const int cnt = offs[e + 1] - off;

  const int cn = tid & 63;
  const int ck = tid >> 6;

  const float* b2p = w2 + (size_t)e * (I_ * H_) + (size_t)(tid >> 4) * H_ + n0 + (tid & 15) * 4;

  for (int mb = 0; mb < cnt; mb += 256) {
    const int m_here = (cnt - mb) < 256 ? (cnt - mb) : 256;
    const bool active = (wv * 64) < m_here;

    const unsigned short* aF[4];
#pragma unroll
    for (int mf = 0; mf < 4; ++mf) {
      int row = off + mb + wv * 64 + mf * 16 + ln;
      row = row < (T_ - 1) ? row : (T_ - 1);
      aF[mf] = h + (size_t)row * I_ + lq * 8;
    }

    auto STGB = [&](int kt, int buf) {
#pragma unroll
      for (int r = 0; r < 2; ++r)
        gload16(b2p + (size_t)(kt * 32 + r * 16) * H_, &Bf[buf][tid * 4 + r * 1024]);
    };

    floatx4 acc[4][4];
#pragma unroll
    for (int i2 = 0; i2 < 4; ++i2)
#pragma unroll
      for (int j2 = 0; j2 < 4; ++j2) acc[i2][j2] = (floatx4){0.f, 0.f, 0.f, 0.f};

    const int NK = I_ / 32;  // 24
    STGB(0, 0);
    STGB(1, 1);
    for (int kt = 0; kt < NK; ++kt) {
      const int cur = kt & 1;
      if (kt == NK - 1) asm volatile("s_waitcnt vmcnt(0)" ::: "memory");
      else              asm volatile("s_waitcnt vmcnt(2)" ::: "memory");
      __builtin_amdgcn_s_barrier();
      asm volatile("" ::: "memory");

      {
        uint32_t dw[4];
#pragma unroll
        for (int d = 0; d < 4; ++d) {
          float v0 = Bf[cur][(ck * 8 + 2 * d) * 64 + cn];
          float v1 = Bf[cur][(ck * 8 + 2 * d + 1) * 64 + cn];
          dw[d] = (uint32_t)f2bf(v0) | ((uint32_t)f2bf(v1) << 16);
        }
        *(uint4*)&Bh[(size_t)bslot(cn, ck) * 8] = make_uint4(dw[0], dw[1], dw[2], dw[3]);
      }
      asm volatile("s_waitcnt lgkmcnt(0)" ::: "memory");
      __builtin_amdgcn_s_barrier();
      asm volatile("" ::: "memory");

      bf16x8 af[4];
      if (active) {
#pragma unroll
        for (int mf = 0; mf < 4; ++mf) af[mf] = *(const bf16x8*)(aF[mf] + kt * 32);
      }
      asm volatile("" ::: "memory");
      if (kt + 2 < NK) STGB(kt + 2, cur);
      asm volatile("" ::: "memory");

      if (active) {
        bf16x8 bF[4];
#pragma unroll
        for (int nf = 0; nf < 4; ++nf)
          bF[nf] = *(const bf16x8*)&Bh[(size_t)bslot(nf * 16 + ln, lq) * 8];
#pragma unroll
        for (int mf = 0; mf < 4; ++mf)
#pragma unroll
          for (int nf = 0; nf < 4; ++nf)
            acc[mf][nf] = __builtin_amdgcn_mfma_f32_16x16x32_bf16(af[mf], bF[nf], acc[mf][nf], 0, 0, 0);
      }
    }

    if (active) {
#pragma unroll
      for (int mf = 0; mf < 4; ++mf)
#pragma unroll
        for (int nf = 0; nf < 4; ++nf)
#pragma unroll
          for (int r = 0; r < 4; ++r) {
            int row_l = wv * 64 + mf * 16 + lq * 4 + r;
            if (row_l < m_here)
              out[(size_t)(off + mb + row_l) * H_ + n0 + nf * 16 + ln] = acc[mf][nf][r];
          }
    }
    asm volatile("s_waitcnt vmcnt(0)" ::: "memory");
  }
}

extern "C" void kernel_launch(void* const* d_in, const int* in_sizes, int n_in,
                              void* d_out, int out_size, void* d_ws, size_t ws_size,
                              hipStream_t stream) {
  const float* x  = (const float*)d_in[0];
  const float* w1 = (const float*)d_in[1];
  const float* w2 = (const float*)d_in[2];
  const float* w3 = (const float*)d_in[3];
  const int* cnts = (const int*)d_in[4];
  float* out = (float*)d_out;

  char* ws = (char*)d_ws;
  int* offs = (int*)ws;                                        // 65 ints
  unsigned short* xb = (unsigned short*)(ws + 1024);           // 16 MB  (T_*H_ bf16)
  unsigned short* h  = (unsigned short*)(ws + 1024 + (size_t)T_ * H_ * 2);  // 12 MB (T_*I_ bf16)

  k_prep<<<(T_ * H_) / (256 * 4), 256, 0, stream>>>(x, xb, cnts, offs);
  k_gemm1<<<E_ * (I_ / 64), 256, 0, stream>>>(xb, w1, w3, h, offs);
  k_gemm2<<<E_ * (H_ / 64), 256, 0, stream>>>(h, w2, out, offs);
}